// Round 1
// baseline (2945.059 us; speedup 1.0000x reference)
//
#include <hip/hip_runtime.h>
#include <math.h>

#define NH 256

static __device__ __forceinline__ float wred_sum(float v){
  #pragma unroll
  for (int o = 32; o > 0; o >>= 1) v += __shfl_xor(v, o, 64);
  return v;
}

// ---------------- prep: hx = log(x+1), ea = log(edge_attr+1) ----------------
__global__ void prep_kernel(const float* __restrict__ x, const float* __restrict__ ea_in,
                            float* __restrict__ hx, float* __restrict__ ea,
                            int nx, int ne){
  int i = blockIdx.x * 256 + threadIdx.x;
  if (i < nx) hx[i] = logf(x[i] + 1.f);
  if (i < ne) ea[i] = logf(ea_in[i] + 1.f);
}

// ---------------- CSR build ----------------
__global__ void zero_kernel(int* __restrict__ c, int n){
  int i = blockIdx.x * 256 + threadIdx.x;
  if (i < n) c[i] = 0;
}

__global__ void hist_kernel(const int* __restrict__ dst, int* __restrict__ counts, int E){
  int i = blockIdx.x * 256 + threadIdx.x;
  if (i < E) atomicAdd(&counts[dst[i]], 1);
}

__global__ __launch_bounds__(1024) void scan_kernel(const int* __restrict__ counts,
                                                    int* __restrict__ row_ptr,
                                                    int* __restrict__ cursor, int N){
  __shared__ int sh[1024];
  __shared__ int carry_s;
  int t = threadIdx.x;
  if (t == 0) carry_s = 0;
  __syncthreads();
  for (int base = 0; base < N; base += 1024){
    int i = base + t;
    int v = (i < N) ? counts[i] : 0;
    sh[t] = v;
    __syncthreads();
    for (int o = 1; o < 1024; o <<= 1){
      int add = (t >= o) ? sh[t - o] : 0;
      __syncthreads();
      sh[t] += add;
      __syncthreads();
    }
    int incl = sh[t];
    int carry = carry_s;
    if (i < N){ int ex = carry + incl - v; row_ptr[i] = ex; cursor[i] = ex; }
    __syncthreads();
    if (t == 1023) carry_s = carry + incl;
    __syncthreads();
  }
  if (t == 0) row_ptr[N] = carry_s;
}

__global__ void scatter_kernel(const int* __restrict__ dst, int* __restrict__ cursor,
                               int* __restrict__ eids, int E){
  int i = blockIdx.x * 256 + threadIdx.x;
  if (i < E){
    int pos = atomicAdd(&cursor[dst[i]], 1);
    eids[pos] = i;
  }
}

// ---------------- head helper: wl_scale[c] = sum_j Wl[c][j]*scale[j] ----------------
__global__ void wlscale_kernel(const float* __restrict__ Wl, const float* __restrict__ bl,
                               const float* __restrict__ scale, float* __restrict__ wlsc){
  int c = threadIdx.x;
  float s = 0.f;
  #pragma unroll
  for (int j = 0; j < 8; j++) s += Wl[c * 8 + j] * scale[j];
  wlsc[c] = s;
  if (c == 0){
    float b = 0.f;
    #pragma unroll
    for (int j = 0; j < 8; j++) b += bl[j] * scale[j];
    wlsc[256] = b;
  }
}

// ---------------- conv1 GEMMs: [N,16] x [16,256] x4 ----------------
__global__ __launch_bounds__(256) void gemm1_kernel(
    const float* __restrict__ A,
    const float* __restrict__ W0, const float* __restrict__ W1,
    const float* __restrict__ W2, const float* __restrict__ W3,
    const float* __restrict__ B0, const float* __restrict__ B1,
    const float* __restrict__ B2, const float* __restrict__ B3,
    float* __restrict__ O0, float* __restrict__ O1,
    float* __restrict__ O2, float* __restrict__ O3, int N)
{
  __shared__ float As[64][16];
  int nb = blockIdx.x * 64;
  {
    int row = nb + (threadIdx.x >> 2);
    int qq = (threadIdx.x & 3) * 4;
    float4 a = make_float4(0.f, 0.f, 0.f, 0.f);
    if (row < N) a = *(const float4*)&A[row * 16 + qq];
    *(float4*)&As[threadIdx.x >> 2][qq] = a;
  }
  __syncthreads();
  int col = threadIdx.x;
  #pragma unroll
  for (int w = 0; w < 4; w++){
    const float* W  = (w == 0) ? W0 : (w == 1) ? W1 : (w == 2) ? W2 : W3;
    const float* Bi = (w == 0) ? B0 : (w == 1) ? B1 : (w == 2) ? B2 : B3;
    float*       O  = (w == 0) ? O0 : (w == 1) ? O1 : (w == 2) ? O2 : O3;
    float wr[16];
    #pragma unroll
    for (int kk = 0; kk < 16; kk++) wr[kk] = W[kk * 256 + col];
    float bias = Bi[col];
    for (int r = 0; r < 64; r++){
      int row = nb + r;
      if (row >= N) break;
      float acc = bias;
      #pragma unroll
      for (int kk = 0; kk < 16; kk++) acc += As[r][kk] * wr[kk];
      O[row * 256 + col] = acc;
    }
  }
}

// ---------------- main GEMMs: q,k,v,s = h2 @ W + b  (fp32 tiled) ----------------
// grid: (ceil(M/64), 16)  blockIdx.y: weight = y>>2, col-tile = (y&3)*64
__global__ __launch_bounds__(256) void gemm_qkvs_kernel(
    const float* __restrict__ A,
    const float* __restrict__ Wq, const float* __restrict__ Wk,
    const float* __restrict__ Wv, const float* __restrict__ Ws,
    const float* __restrict__ bq, const float* __restrict__ bk,
    const float* __restrict__ bv, const float* __restrict__ bs,
    float* __restrict__ Oq, float* __restrict__ Ok,
    float* __restrict__ Ov, float* __restrict__ Os, int M)
{
  __shared__ float As[32][68];   // transposed A tile, padded (272B rows keep 16B align)
  __shared__ float Bs[32][64];
  int w  = blockIdx.y >> 2;
  int n0 = (blockIdx.y & 3) * 64;
  const float* W  = (w == 0) ? Wq : (w == 1) ? Wk : (w == 2) ? Wv : Ws;
  const float* Bi = (w == 0) ? bq : (w == 1) ? bk : (w == 2) ? bv : bs;
  float*       O  = (w == 0) ? Oq : (w == 1) ? Ok : (w == 2) ? Ov : Os;
  int m0 = blockIdx.x * 64;
  int tid = threadIdx.x;
  int tx = tid & 15, ty = tid >> 4;
  int ar = tid >> 3, ak = (tid & 7) << 2;
  int br = tid >> 4, bn = (tid & 15) << 2;
  float acc[4][4] = {};
  for (int k0 = 0; k0 < 256; k0 += 32){
    #pragma unroll
    for (int rr = 0; rr < 64; rr += 32){
      int row = m0 + ar + rr;
      float4 a = make_float4(0.f, 0.f, 0.f, 0.f);
      if (row < M) a = *(const float4*)&A[row * 256 + k0 + ak];
      As[ak + 0][ar + rr] = a.x; As[ak + 1][ar + rr] = a.y;
      As[ak + 2][ar + rr] = a.z; As[ak + 3][ar + rr] = a.w;
    }
    #pragma unroll
    for (int kk = 0; kk < 32; kk += 16){
      float4 b = *(const float4*)&W[(k0 + br + kk) * 256 + n0 + bn];
      *(float4*)&Bs[br + kk][bn] = b;
    }
    __syncthreads();
    #pragma unroll
    for (int k = 0; k < 32; k++){
      float4 av  = *(const float4*)&As[k][ty * 4];
      float4 bv4 = *(const float4*)&Bs[k][tx * 4];
      acc[0][0] += av.x * bv4.x; acc[0][1] += av.x * bv4.y; acc[0][2] += av.x * bv4.z; acc[0][3] += av.x * bv4.w;
      acc[1][0] += av.y * bv4.x; acc[1][1] += av.y * bv4.y; acc[1][2] += av.y * bv4.z; acc[1][3] += av.y * bv4.w;
      acc[2][0] += av.z * bv4.x; acc[2][1] += av.z * bv4.y; acc[2][2] += av.z * bv4.z; acc[2][3] += av.z * bv4.w;
      acc[3][0] += av.w * bv4.x; acc[3][1] += av.w * bv4.y; acc[3][2] += av.w * bv4.z; acc[3][3] += av.w * bv4.w;
    }
    __syncthreads();
  }
  float4 bias = *(const float4*)&Bi[n0 + tx * 4];
  #pragma unroll
  for (int i = 0; i < 4; i++){
    int row = m0 + ty * 4 + i;
    if (row < M){
      float4 o;
      o.x = acc[i][0] + bias.x; o.y = acc[i][1] + bias.y;
      o.z = acc[i][2] + bias.z; o.w = acc[i][3] + bias.w;
      *(float4*)&O[row * 256 + n0 + tx * 4] = o;
    }
  }
}

// ---------------- attention aggregation + residual + fused std/relu ----------------
// one wave per destination node, online softmax over its CSR edge list
__global__ __launch_bounds__(256) void agg_kernel(
    const float* __restrict__ q, const float* __restrict__ k,
    const float* __restrict__ v, const float* __restrict__ slin,
    const float* __restrict__ ea, const float* __restrict__ We,
    const int* __restrict__ src, const int* __restrict__ row_ptr,
    const int* __restrict__ eids,
    const float* __restrict__ h_in, float* __restrict__ h_out,
    float* __restrict__ h2_out, int RESID, int N)
{
  __shared__ float We_s[4 * 256];
  for (int i = threadIdx.x; i < 1024; i += 256) We_s[i] = We[i];
  __syncthreads();
  int wid = threadIdx.x >> 6, lane = threadIdx.x & 63;
  int n = blockIdx.x * 4 + wid;
  if (n >= N) return;
  int c0 = lane * 4;
  float4 qv = *(const float4*)&q[n * 256 + c0];
  float m = -INFINITY, ssum = 0.f;
  float a0 = 0.f, a1 = 0.f, a2 = 0.f, a3 = 0.f;
  int e0 = row_ptr[n], e1 = row_ptr[n + 1];
  for (int ie = e0; ie < e1; ++ie){
    int e = eids[ie];
    int s = src[e];
    float4 eav = *(const float4*)&ea[e * 4];
    float em0 = eav.x * We_s[c0 + 0] + eav.y * We_s[256 + c0 + 0] + eav.z * We_s[512 + c0 + 0] + eav.w * We_s[768 + c0 + 0];
    float em1 = eav.x * We_s[c0 + 1] + eav.y * We_s[256 + c0 + 1] + eav.z * We_s[512 + c0 + 1] + eav.w * We_s[768 + c0 + 1];
    float em2 = eav.x * We_s[c0 + 2] + eav.y * We_s[256 + c0 + 2] + eav.z * We_s[512 + c0 + 2] + eav.w * We_s[768 + c0 + 2];
    float em3 = eav.x * We_s[c0 + 3] + eav.y * We_s[256 + c0 + 3] + eav.z * We_s[512 + c0 + 3] + eav.w * We_s[768 + c0 + 3];
    float4 kv = *(const float4*)&k[s * 256 + c0];
    float4 vv = *(const float4*)&v[s * 256 + c0];
    float part = qv.x * (kv.x + em0) + qv.y * (kv.y + em1) + qv.z * (kv.z + em2) + qv.w * (kv.w + em3);
    part = wred_sum(part);
    float alpha = part * (1.f / 16.f);
    float mn = fmaxf(m, alpha);
    float corr = expf(m - mn);      // m = -inf on first edge -> 0
    float wgt  = expf(alpha - mn);
    ssum = ssum * corr + wgt;
    a0 = a0 * corr + wgt * (vv.x + em0);
    a1 = a1 * corr + wgt * (vv.y + em1);
    a2 = a2 * corr + wgt * (vv.z + em2);
    a3 = a3 * corr + wgt * (vv.w + em3);
    m = mn;
  }
  float inv = 1.f / (ssum + 1e-16f);
  float4 sl = *(const float4*)&slin[n * 256 + c0];
  float y0 = a0 * inv + sl.x;
  float y1 = a1 * inv + sl.y;
  float y2 = a2 * inv + sl.z;
  float y3 = a3 * inv + sl.w;
  float o0, o1, o2, o3;
  if (RESID){
    float4 hp = *(const float4*)&h_in[n * 256 + c0];
    o0 = hp.x + y0; o1 = hp.y + y1; o2 = hp.z + y2; o3 = hp.w + y3;
  } else {
    o0 = y0; o1 = y1; o2 = y2; o3 = y3;
  }
  float4 ho; ho.x = o0; ho.y = o1; ho.z = o2; ho.w = o3;
  *(float4*)&h_out[n * 256 + c0] = ho;
  // fused std (ddof=1) + relu for the next block's input
  float mean = wred_sum(o0 + o1 + o2 + o3) * (1.f / 256.f);
  float d0 = o0 - mean, d1 = o1 - mean, d2 = o2 - mean, d3 = o3 - mean;
  float var = wred_sum(d0 * d0 + d1 * d1 + d2 * d2 + d3 * d3) * (1.f / 255.f);
  float invstd = 1.f / sqrtf(var);
  float4 h2;
  h2.x = fmaxf(o0 * invstd, 0.f);
  h2.y = fmaxf(o1 * invstd, 0.f);
  h2.z = fmaxf(o2 * invstd, 0.f);
  h2.w = fmaxf(o3 * invstd, 0.f);
  *(float4*)&h2_out[n * 256 + c0] = h2;
}

// ---------------- output head ----------------
__global__ __launch_bounds__(256) void head_kernel(const float* __restrict__ h,
                                                   const float* __restrict__ wlsc,
                                                   float* __restrict__ out, int N){
  int wid = threadIdx.x >> 6, lane = threadIdx.x & 63;
  int n = blockIdx.x * 4 + wid;
  if (n >= N) return;
  int c0 = lane * 4;
  float4 hv = *(const float4*)&h[n * 256 + c0];
  float4 wv = *(const float4*)&wlsc[c0];
  float p = hv.x * wv.x + hv.y * wv.y + hv.z * wv.z + hv.w * wv.w;
  p = wred_sum(p);
  if (lane == 0) out[n] = p * (1.f / sqrtf(15.f)) + wlsc[256];
}

// ---------------- launch ----------------
extern "C" void kernel_launch(void* const* d_in, const int* in_sizes, int n_in,
                              void* d_out, int out_size, void* d_ws, size_t ws_size,
                              hipStream_t stream)
{
  const float* x     = (const float*)d_in[0];
  const int*   eidx  = (const int*)d_in[1];
  const float* eattr = (const float*)d_in[2];
  const float* Wq1 = (const float*)d_in[3];  const float* bq1 = (const float*)d_in[4];
  const float* Wk1 = (const float*)d_in[5];  const float* bk1 = (const float*)d_in[6];
  const float* Wv1 = (const float*)d_in[7];  const float* bv1 = (const float*)d_in[8];
  const float* We1 = (const float*)d_in[9];
  const float* Ws1 = (const float*)d_in[10]; const float* bs1 = (const float*)d_in[11];
  const float* Wq = (const float*)d_in[12];  const float* bq = (const float*)d_in[13];
  const float* Wk = (const float*)d_in[14];  const float* bk = (const float*)d_in[15];
  const float* Wv = (const float*)d_in[16];  const float* bv = (const float*)d_in[17];
  const float* We = (const float*)d_in[18];
  const float* Ws = (const float*)d_in[19];  const float* bs = (const float*)d_in[20];
  const float* Wl = (const float*)d_in[21];  const float* bl = (const float*)d_in[22];
  const float* scale = (const float*)d_in[23];
  (void)eattr; (void)scale; (void)n_in; (void)ws_size;

  int N = in_sizes[0] / 16;
  int E = in_sizes[2] / 4;
  float* out = (float*)d_out;
  (void)out_size;

  char* p = (char*)d_ws;
  auto alloc = [&](size_t bytes) -> char* {
    char* r = p; p += (bytes + 255) & ~(size_t)255; return r;
  };
  float* hx   = (float*)alloc((size_t)N * 16 * 4);
  float* ea   = (float*)alloc((size_t)E * 4 * 4);
  float* h    = (float*)alloc((size_t)N * 256 * 4);
  float* h2   = (float*)alloc((size_t)N * 256 * 4);
  float* q    = (float*)alloc((size_t)N * 256 * 4);
  float* k    = (float*)alloc((size_t)N * 256 * 4);
  float* v    = (float*)alloc((size_t)N * 256 * 4);
  float* sl   = (float*)alloc((size_t)N * 256 * 4);
  float* wlsc = (float*)alloc(257 * 4);
  int* counts  = (int*)alloc((size_t)N * 4);
  int* cursor  = (int*)alloc((size_t)N * 4);
  int* row_ptr = (int*)alloc(((size_t)N + 1) * 4);
  int* eids    = (int*)alloc((size_t)E * 4);

  const int* srcp = eidx;
  const int* dstp = eidx + E;

  int nx = N * 16, ne = E * 4;
  int prep_blocks = (ne > nx ? ne : nx + 255) > 0 ? ((ne > nx ? ne : nx) + 255) / 256 : 1;

  zero_kernel<<<(N + 255) / 256, 256, 0, stream>>>(counts, N);
  prep_kernel<<<prep_blocks, 256, 0, stream>>>(x, (const float*)d_in[2], hx, ea, nx, ne);
  hist_kernel<<<(E + 255) / 256, 256, 0, stream>>>(dstp, counts, E);
  scan_kernel<<<1, 1024, 0, stream>>>(counts, row_ptr, cursor, N);
  scatter_kernel<<<(E + 255) / 256, 256, 0, stream>>>(dstp, cursor, eids, E);
  wlscale_kernel<<<1, 256, 0, stream>>>(Wl, bl, scale, wlsc);

  // conv1
  gemm1_kernel<<<(N + 63) / 64, 256, 0, stream>>>(hx, Wq1, Wk1, Wv1, Ws1,
                                                  bq1, bk1, bv1, bs1, q, k, v, sl, N);
  agg_kernel<<<(N + 3) / 4, 256, 0, stream>>>(q, k, v, sl, ea, We1, srcp, row_ptr, eids,
                                              h, h, h2, 0, N);

  // 15 residual blocks
  for (int l = 0; l < 15; l++){
    gemm_qkvs_kernel<<<dim3((N + 63) / 64, 16), 256, 0, stream>>>(
        h2,
        Wq + (size_t)l * 256 * 256, Wk + (size_t)l * 256 * 256,
        Wv + (size_t)l * 256 * 256, Ws + (size_t)l * 256 * 256,
        bq + (size_t)l * 256, bk + (size_t)l * 256,
        bv + (size_t)l * 256, bs + (size_t)l * 256,
        q, k, v, sl, N);
    agg_kernel<<<(N + 3) / 4, 256, 0, stream>>>(q, k, v, sl, ea, We + (size_t)l * 4 * 256,
                                                srcp, row_ptr, eids, h, h, h2, 1, N);
  }

  head_kernel<<<(N + 3) / 4, 256, 0, stream>>>(h, wlsc, out, N);
}

// Round 2
// 1425.995 us; speedup vs baseline: 2.0653x; 2.0653x over previous
//
#include <hip/hip_runtime.h>
#include <math.h>

typedef short bf16x8 __attribute__((ext_vector_type(8)));
typedef float f32x4 __attribute__((ext_vector_type(4)));

static __device__ __forceinline__ float wred_sum(float v){
  #pragma unroll
  for (int o = 32; o > 0; o >>= 1) v += __shfl_xor(v, o, 64);
  return v;
}

static __device__ __forceinline__ unsigned short f2bf(float x){
  union { float f; unsigned int u; } c; c.f = x;
  unsigned int u = c.u;
  return (unsigned short)((u + 0x7FFFu + ((u >> 16) & 1u)) >> 16);
}

// ---------------- prep: hx = log(x+1), ea = log(edge_attr+1) ----------------
__global__ void prep_kernel(const float* __restrict__ x, const float* __restrict__ ea_in,
                            float* __restrict__ hx, float* __restrict__ ea,
                            int nx, int ne){
  int i = blockIdx.x * 256 + threadIdx.x;
  if (i < nx) hx[i] = logf(x[i] + 1.f);
  if (i < ne) ea[i] = logf(ea_in[i] + 1.f);
}

// ---------------- CSR build ----------------
__global__ void zero_kernel(int* __restrict__ c, int n){
  int i = blockIdx.x * 256 + threadIdx.x;
  if (i < n) c[i] = 0;
}

__global__ void hist_kernel(const int* __restrict__ dst, int* __restrict__ counts, int E){
  int i = blockIdx.x * 256 + threadIdx.x;
  if (i < E) atomicAdd(&counts[dst[i]], 1);
}

__global__ __launch_bounds__(1024) void scan_kernel(const int* __restrict__ counts,
                                                    int* __restrict__ row_ptr,
                                                    int* __restrict__ cursor, int N){
  __shared__ int sh[1024];
  __shared__ int carry_s;
  int t = threadIdx.x;
  if (t == 0) carry_s = 0;
  __syncthreads();
  for (int base = 0; base < N; base += 1024){
    int i = base + t;
    int v = (i < N) ? counts[i] : 0;
    sh[t] = v;
    __syncthreads();
    for (int o = 1; o < 1024; o <<= 1){
      int add = (t >= o) ? sh[t - o] : 0;
      __syncthreads();
      sh[t] += add;
      __syncthreads();
    }
    int incl = sh[t];
    int carry = carry_s;
    if (i < N){ int ex = carry + incl - v; row_ptr[i] = ex; cursor[i] = ex; }
    __syncthreads();
    if (t == 1023) carry_s = carry + incl;
    __syncthreads();
  }
  if (t == 0) row_ptr[N] = carry_s;
}

__global__ void scatter_kernel(const int* __restrict__ dst, int* __restrict__ cursor,
                               int* __restrict__ eids, int E){
  int i = blockIdx.x * 256 + threadIdx.x;
  if (i < E){
    int pos = atomicAdd(&cursor[dst[i]], 1);
    eids[pos] = i;
  }
}

// ---------------- head helper ----------------
__global__ void wlscale_kernel(const float* __restrict__ Wl, const float* __restrict__ bl,
                               const float* __restrict__ scale, float* __restrict__ wlsc){
  int c = threadIdx.x;
  float s = 0.f;
  #pragma unroll
  for (int j = 0; j < 8; j++) s += Wl[c * 8 + j] * scale[j];
  wlsc[c] = s;
  if (c == 0){
    float b = 0.f;
    #pragma unroll
    for (int j = 0; j < 8; j++) b += bl[j] * scale[j];
    wlsc[256] = b;
  }
}

// ---------------- weight pack: Wp[l][ncat][k] = W(l)[k][n] bf16 (transpose) --------
// grid (8 ktiles, 32 ntiles, 15), block 256
__global__ __launch_bounds__(256) void pack_w_kernel(
    const float* __restrict__ Wq, const float* __restrict__ Wk,
    const float* __restrict__ Wv, const float* __restrict__ Ws,
    unsigned short* __restrict__ Wp)
{
  __shared__ float t[32][33];
  int l   = blockIdx.z;
  int k0  = blockIdx.x * 32;
  int n0g = blockIdx.y * 32;       // 0..1023 over concat(q,k,v,s)
  int w   = n0g >> 8;
  int n0  = n0g & 255;
  const float* W = ((w == 0) ? Wq : (w == 1) ? Wk : (w == 2) ? Wv : Ws) + (size_t)l * 65536;
  int rr = threadIdx.x >> 3;        // 0..31 (k row)
  int cc = (threadIdx.x & 7) * 4;   // 0..28 (n col)
  float4 vv = *(const float4*)&W[(size_t)(k0 + rr) * 256 + n0 + cc];
  t[rr][cc + 0] = vv.x; t[rr][cc + 1] = vv.y; t[rr][cc + 2] = vv.z; t[rr][cc + 3] = vv.w;
  __syncthreads();
  // write transposed: rows rr = n local, cols cc..cc+3 = k local
  ushort4 o;
  o.x = f2bf(t[cc + 0][rr]);
  o.y = f2bf(t[cc + 1][rr]);
  o.z = f2bf(t[cc + 2][rr]);
  o.w = f2bf(t[cc + 3][rr]);
  *(ushort4*)&Wp[(size_t)l * 262144 + (size_t)(n0g + rr) * 256 + k0 + cc] = o;
}

__global__ void pack_b_kernel(const float* __restrict__ bq, const float* __restrict__ bk,
                              const float* __restrict__ bv, const float* __restrict__ bs,
                              float* __restrict__ bp){
  int i = blockIdx.x * 256 + threadIdx.x;   // over 15*256
  if (i < 15 * 256){
    int l = i >> 8, n = i & 255;
    bp[l * 1024 + 0   + n] = bq[i];
    bp[l * 1024 + 256 + n] = bk[i];
    bp[l * 1024 + 512 + n] = bv[i];
    bp[l * 1024 + 768 + n] = bs[i];
  }
}

// ---------------- conv1 GEMMs: [N,16] x [16,256] x4 -> O[N][1024] ----------------
__global__ __launch_bounds__(256) void gemm1_kernel(
    const float* __restrict__ A,
    const float* __restrict__ W0, const float* __restrict__ W1,
    const float* __restrict__ W2, const float* __restrict__ W3,
    const float* __restrict__ B0, const float* __restrict__ B1,
    const float* __restrict__ B2, const float* __restrict__ B3,
    float* __restrict__ O, int N)
{
  __shared__ float As[64][16];
  int nb = blockIdx.x * 64;
  {
    int row = nb + (threadIdx.x >> 2);
    int qq = (threadIdx.x & 3) * 4;
    float4 a = make_float4(0.f, 0.f, 0.f, 0.f);
    if (row < N) a = *(const float4*)&A[row * 16 + qq];
    *(float4*)&As[threadIdx.x >> 2][qq] = a;
  }
  __syncthreads();
  int col = threadIdx.x;
  #pragma unroll
  for (int w = 0; w < 4; w++){
    const float* W  = (w == 0) ? W0 : (w == 1) ? W1 : (w == 2) ? W2 : W3;
    const float* Bi = (w == 0) ? B0 : (w == 1) ? B1 : (w == 2) ? B2 : B3;
    float wr[16];
    #pragma unroll
    for (int kk = 0; kk < 16; kk++) wr[kk] = W[kk * 256 + col];
    float bias = Bi[col];
    for (int r = 0; r < 64; r++){
      int row = nb + r;
      if (row >= N) break;
      float acc = bias;
      #pragma unroll
      for (int kk = 0; kk < 16; kk++) acc += As[r][kk] * wr[kk];
      O[(size_t)row * 1024 + w * 256 + col] = acc;
    }
  }
}

// ---------------- main MFMA GEMM: O[M,1024] = A(bf16)[M,256] @ Wcat + b ----------
// 128x128 tile, BK=64, 4 waves (2x2), global_load_lds w16, XOR-swizzled LDS.
__global__ __launch_bounds__(256, 2) void gemm_mfma_kernel(
    const unsigned short* __restrict__ A,   // [Mpad][256] bf16
    const unsigned short* __restrict__ Wp,  // [1024][256] bf16 (W^T for this layer)
    const float* __restrict__ bp,           // [1024] bias
    float* __restrict__ O,                  // [M][1024]
    int M)
{
  __shared__ unsigned short lds[2 * 128 * 64];   // A:[128][64], B:[128][64]
  unsigned short* ldsA = lds;
  unsigned short* ldsB = lds + 128 * 64;
  const int tid  = threadIdx.x;
  const int wave = tid >> 6, lane = tid & 63;
  const int wm = wave >> 1, wn = wave & 1;
  const int m0 = blockIdx.x * 128;
  const int n0 = blockIdx.y * 128;

  f32x4 acc[4][4] = {};

  // staging lane geometry: each global_load_lds covers 8 rows x 64 cols (1KB)
  const int srow  = lane >> 3;                 // 0..7
  const int sc16  = lane & 7;                  // 16B slot within row
  const int skgrp = sc16 ^ (srow & 7);         // pre-swizzled logical k-group

  for (int k0 = 0; k0 < 256; k0 += 64){
    #pragma unroll
    for (int it = 0; it < 4; ++it){
      int lrow = wave * 32 + it * 8;           // LDS row base (uniform in wave)
      const unsigned short* gA = A + (size_t)(m0 + lrow + srow) * 256 + k0 + skgrp * 8;
      __builtin_amdgcn_global_load_lds((const __attribute__((address_space(1))) unsigned int*)gA,
          (__attribute__((address_space(3))) unsigned int*)(ldsA + lrow * 64), 16, 0, 0);
      const unsigned short* gB = Wp + (size_t)(n0 + lrow + srow) * 256 + k0 + skgrp * 8;
      __builtin_amdgcn_global_load_lds((const __attribute__((address_space(1))) unsigned int*)gB,
          (__attribute__((address_space(3))) unsigned int*)(ldsB + lrow * 64), 16, 0, 0);
    }
    __syncthreads();

    bf16x8 af[4][2], bfr[4][2];
    #pragma unroll
    for (int mb = 0; mb < 4; ++mb){
      int r = wm * 64 + mb * 16 + (lane & 15);
      #pragma unroll
      for (int ks = 0; ks < 2; ++ks){
        int kg = ks * 4 + (lane >> 4);
        af[mb][ks] = *(const bf16x8*)&ldsA[r * 64 + ((kg ^ (r & 7)) * 8)];
      }
    }
    #pragma unroll
    for (int nb = 0; nb < 4; ++nb){
      int r = wn * 64 + nb * 16 + (lane & 15);
      #pragma unroll
      for (int ks = 0; ks < 2; ++ks){
        int kg = ks * 4 + (lane >> 4);
        bfr[nb][ks] = *(const bf16x8*)&ldsB[r * 64 + ((kg ^ (r & 7)) * 8)];
      }
    }
    #pragma unroll
    for (int mb = 0; mb < 4; ++mb){
      #pragma unroll
      for (int nb = 0; nb < 4; ++nb){
        acc[mb][nb] = __builtin_amdgcn_mfma_f32_16x16x32_bf16(af[mb][0], bfr[nb][0], acc[mb][nb], 0, 0, 0);
        acc[mb][nb] = __builtin_amdgcn_mfma_f32_16x16x32_bf16(af[mb][1], bfr[nb][1], acc[mb][nb], 0, 0, 0);
      }
    }
    __syncthreads();
  }

  // epilogue: bias + guarded store. D layout: col=lane&15, row=(lane>>4)*4+r
  #pragma unroll
  for (int nb = 0; nb < 4; ++nb){
    int col = n0 + wn * 64 + nb * 16 + (lane & 15);
    float bias = bp[col];
    #pragma unroll
    for (int mb = 0; mb < 4; ++mb){
      #pragma unroll
      for (int r4 = 0; r4 < 4; ++r4){
        int row = m0 + wm * 64 + mb * 16 + (lane >> 4) * 4 + r4;
        if (row < M) O[(size_t)row * 1024 + col] = acc[mb][nb][r4] + bias;
      }
    }
  }
}

// ---------------- attention aggregation + residual + fused std/relu + bf16 h2 ----
__global__ __launch_bounds__(256) void agg_kernel(
    const float* __restrict__ O,    // [N][1024]: q|k|v|s
    const float* __restrict__ ea, const float* __restrict__ We,
    const int* __restrict__ src, const int* __restrict__ row_ptr,
    const int* __restrict__ eids,
    const float* __restrict__ h_in, float* __restrict__ h_out,
    unsigned short* __restrict__ h2b, int RESID, int N)
{
  __shared__ float We_s[4 * 256];
  for (int i = threadIdx.x; i < 1024; i += 256) We_s[i] = We[i];
  __syncthreads();
  int wid = threadIdx.x >> 6, lane = threadIdx.x & 63;
  int n = blockIdx.x * 4 + wid;
  if (n >= N) return;
  int c0 = lane * 4;
  float4 qv = *(const float4*)&O[(size_t)n * 1024 + c0];
  float m = -INFINITY, ssum = 0.f;
  float a0 = 0.f, a1 = 0.f, a2 = 0.f, a3 = 0.f;
  int e0 = row_ptr[n], e1 = row_ptr[n + 1];
  for (int ie = e0; ie < e1; ++ie){
    int e = eids[ie];
    int s = src[e];
    float4 eav = *(const float4*)&ea[e * 4];
    float em0 = eav.x * We_s[c0 + 0] + eav.y * We_s[256 + c0 + 0] + eav.z * We_s[512 + c0 + 0] + eav.w * We_s[768 + c0 + 0];
    float em1 = eav.x * We_s[c0 + 1] + eav.y * We_s[256 + c0 + 1] + eav.z * We_s[512 + c0 + 1] + eav.w * We_s[768 + c0 + 1];
    float em2 = eav.x * We_s[c0 + 2] + eav.y * We_s[256 + c0 + 2] + eav.z * We_s[512 + c0 + 2] + eav.w * We_s[768 + c0 + 2];
    float em3 = eav.x * We_s[c0 + 3] + eav.y * We_s[256 + c0 + 3] + eav.z * We_s[512 + c0 + 3] + eav.w * We_s[768 + c0 + 3];
    float4 kv = *(const float4*)&O[(size_t)s * 1024 + 256 + c0];
    float4 vv = *(const float4*)&O[(size_t)s * 1024 + 512 + c0];
    float part = qv.x * (kv.x + em0) + qv.y * (kv.y + em1) + qv.z * (kv.z + em2) + qv.w * (kv.w + em3);
    part = wred_sum(part);
    float alpha = part * (1.f / 16.f);
    float mn = fmaxf(m, alpha);
    float corr = expf(m - mn);
    float wgt  = expf(alpha - mn);
    ssum = ssum * corr + wgt;
    a0 = a0 * corr + wgt * (vv.x + em0);
    a1 = a1 * corr + wgt * (vv.y + em1);
    a2 = a2 * corr + wgt * (vv.z + em2);
    a3 = a3 * corr + wgt * (vv.w + em3);
    m = mn;
  }
  float inv = 1.f / (ssum + 1e-16f);
  float4 sl = *(const float4*)&O[(size_t)n * 1024 + 768 + c0];
  float y0 = a0 * inv + sl.x;
  float y1 = a1 * inv + sl.y;
  float y2 = a2 * inv + sl.z;
  float y3 = a3 * inv + sl.w;
  float o0, o1, o2, o3;
  if (RESID){
    float4 hp = *(const float4*)&h_in[(size_t)n * 256 + c0];
    o0 = hp.x + y0; o1 = hp.y + y1; o2 = hp.z + y2; o3 = hp.w + y3;
  } else {
    o0 = y0; o1 = y1; o2 = y2; o3 = y3;
  }
  float4 ho; ho.x = o0; ho.y = o1; ho.z = o2; ho.w = o3;
  *(float4*)&h_out[(size_t)n * 256 + c0] = ho;
  // fused std (ddof=1) + relu, output as bf16 for next GEMM
  float mean = wred_sum(o0 + o1 + o2 + o3) * (1.f / 256.f);
  float d0 = o0 - mean, d1 = o1 - mean, d2 = o2 - mean, d3 = o3 - mean;
  float var = wred_sum(d0 * d0 + d1 * d1 + d2 * d2 + d3 * d3) * (1.f / 255.f);
  float invstd = 1.f / sqrtf(var);
  ushort4 hb;
  hb.x = f2bf(fmaxf(o0 * invstd, 0.f));
  hb.y = f2bf(fmaxf(o1 * invstd, 0.f));
  hb.z = f2bf(fmaxf(o2 * invstd, 0.f));
  hb.w = f2bf(fmaxf(o3 * invstd, 0.f));
  *(ushort4*)&h2b[(size_t)n * 256 + c0] = hb;
}

// ---------------- output head ----------------
__global__ __launch_bounds__(256) void head_kernel(const float* __restrict__ h,
                                                   const float* __restrict__ wlsc,
                                                   float* __restrict__ out, int N){
  int wid = threadIdx.x >> 6, lane = threadIdx.x & 63;
  int n = blockIdx.x * 4 + wid;
  if (n >= N) return;
  int c0 = lane * 4;
  float4 hv = *(const float4*)&h[(size_t)n * 256 + c0];
  float4 wv = *(const float4*)&wlsc[c0];
  float p = hv.x * wv.x + hv.y * wv.y + hv.z * wv.z + hv.w * wv.w;
  p = wred_sum(p);
  if (lane == 0) out[n] = p * (1.f / sqrtf(15.f)) + wlsc[256];
}

// ---------------- launch ----------------
extern "C" void kernel_launch(void* const* d_in, const int* in_sizes, int n_in,
                              void* d_out, int out_size, void* d_ws, size_t ws_size,
                              hipStream_t stream)
{
  const float* x     = (const float*)d_in[0];
  const int*   eidx  = (const int*)d_in[1];
  const float* Wq1 = (const float*)d_in[3];  const float* bq1 = (const float*)d_in[4];
  const float* Wk1 = (const float*)d_in[5];  const float* bk1 = (const float*)d_in[6];
  const float* Wv1 = (const float*)d_in[7];  const float* bv1 = (const float*)d_in[8];
  const float* We1 = (const float*)d_in[9];
  const float* Ws1 = (const float*)d_in[10]; const float* bs1 = (const float*)d_in[11];
  const float* Wq = (const float*)d_in[12];  const float* bq = (const float*)d_in[13];
  const float* Wk = (const float*)d_in[14];  const float* bk = (const float*)d_in[15];
  const float* Wv = (const float*)d_in[16];  const float* bv = (const float*)d_in[17];
  const float* We = (const float*)d_in[18];
  const float* Ws = (const float*)d_in[19];  const float* bs = (const float*)d_in[20];
  const float* Wl = (const float*)d_in[21];  const float* bl = (const float*)d_in[22];
  const float* scale = (const float*)d_in[23];
  (void)n_in; (void)ws_size;

  int N = in_sizes[0] / 16;
  int E = in_sizes[2] / 4;
  int Mpad = (N + 127) & ~127;
  float* out = (float*)d_out;
  (void)out_size;

  char* p = (char*)d_ws;
  auto alloc = [&](size_t bytes) -> char* {
    char* r = p; p += (bytes + 255) & ~(size_t)255; return r;
  };
  float* hx   = (float*)alloc((size_t)N * 16 * 4);
  float* ea   = (float*)alloc((size_t)E * 4 * 4);
  float* h    = (float*)alloc((size_t)N * 256 * 4);
  unsigned short* h2b = (unsigned short*)alloc((size_t)Mpad * 256 * 2);
  float* O    = (float*)alloc((size_t)N * 1024 * 4);
  unsigned short* Wp  = (unsigned short*)alloc((size_t)15 * 1024 * 256 * 2);
  float* bp   = (float*)alloc((size_t)15 * 1024 * 4);
  float* wlsc = (float*)alloc(257 * 4);
  int* counts  = (int*)alloc((size_t)N * 4);
  int* cursor  = (int*)alloc((size_t)N * 4);
  int* row_ptr = (int*)alloc(((size_t)N + 1) * 4);
  int* eids    = (int*)alloc((size_t)E * 4);

  const int* srcp = eidx;
  const int* dstp = eidx + E;

  int nx = N * 16, ne = E * 4;
  int big = nx > ne ? nx : ne;

  zero_kernel<<<(N + 255) / 256, 256, 0, stream>>>(counts, N);
  prep_kernel<<<(big + 255) / 256, 256, 0, stream>>>(x, (const float*)d_in[2], hx, ea, nx, ne);
  hist_kernel<<<(E + 255) / 256, 256, 0, stream>>>(dstp, counts, E);
  scan_kernel<<<1, 1024, 0, stream>>>(counts, row_ptr, cursor, N);
  scatter_kernel<<<(E + 255) / 256, 256, 0, stream>>>(dstp, cursor, eids, E);
  wlscale_kernel<<<1, 256, 0, stream>>>(Wl, bl, scale, wlsc);
  pack_w_kernel<<<dim3(8, 32, 15), 256, 0, stream>>>(Wq, Wk, Wv, Ws, Wp);
  pack_b_kernel<<<15, 256, 0, stream>>>(bq, bk, bv, bs, bp);

  // conv1
  gemm1_kernel<<<(N + 63) / 64, 256, 0, stream>>>(hx, Wq1, Wk1, Wv1, Ws1,
                                                  bq1, bk1, bv1, bs1, O, N);
  agg_kernel<<<(N + 3) / 4, 256, 0, stream>>>(O, ea, We1, srcp, row_ptr, eids,
                                              h, h, h2b, 0, N);

  // 15 residual blocks
  for (int l = 0; l < 15; l++){
    gemm_mfma_kernel<<<dim3(Mpad / 128, 8), 256, 0, stream>>>(
        h2b, Wp + (size_t)l * 262144, bp + (size_t)l * 1024, O, N);
    agg_kernel<<<(N + 3) / 4, 256, 0, stream>>>(O, ea, We + (size_t)l * 1024,
                                                srcp, row_ptr, eids, h, h, h2b, 1, N);
  }

  head_kernel<<<(N + 3) / 4, 256, 0, stream>>>(h, wlsc, out, N);
}

// Round 3
// 1333.825 us; speedup vs baseline: 2.2080x; 1.0691x over previous
//
#include <hip/hip_runtime.h>
#include <math.h>

typedef short bf16x8 __attribute__((ext_vector_type(8)));
typedef float f32x4 __attribute__((ext_vector_type(4)));

static __device__ __forceinline__ float wred_sum(float v){
  #pragma unroll
  for (int o = 32; o > 0; o >>= 1) v += __shfl_xor(v, o, 64);
  return v;
}

static __device__ __forceinline__ unsigned short f2bf(float x){
  union { float f; unsigned int u; } c; c.f = x;
  unsigned int u = c.u;
  return (unsigned short)((u + 0x7FFFu + ((u >> 16) & 1u)) >> 16);
}

static __device__ __forceinline__ float b2f(unsigned short x){
  union { unsigned int u; float f; } c; c.u = ((unsigned int)x) << 16;
  return c.f;
}

// ---------------- prep: hx = log(x+1), ea = log(edge_attr+1) ----------------
__global__ void prep_kernel(const float* __restrict__ x, const float* __restrict__ ea_in,
                            float* __restrict__ hx, float* __restrict__ ea,
                            int nx, int ne){
  int i = blockIdx.x * 256 + threadIdx.x;
  if (i < nx) hx[i] = logf(x[i] + 1.f);
  if (i < ne) ea[i] = logf(ea_in[i] + 1.f);
}

// ---------------- CSR build ----------------
__global__ void zero_kernel(int* __restrict__ c, int n){
  int i = blockIdx.x * 256 + threadIdx.x;
  if (i < n) c[i] = 0;
}

__global__ void hist_kernel(const int* __restrict__ dst, int* __restrict__ counts, int E){
  int i = blockIdx.x * 256 + threadIdx.x;
  if (i < E) atomicAdd(&counts[dst[i]], 1);
}

__global__ __launch_bounds__(1024) void scan_kernel(const int* __restrict__ counts,
                                                    int* __restrict__ row_ptr,
                                                    int* __restrict__ cursor, int N){
  __shared__ int sh[1024];
  __shared__ int carry_s;
  int t = threadIdx.x;
  if (t == 0) carry_s = 0;
  __syncthreads();
  for (int base = 0; base < N; base += 1024){
    int i = base + t;
    int v = (i < N) ? counts[i] : 0;
    sh[t] = v;
    __syncthreads();
    for (int o = 1; o < 1024; o <<= 1){
      int add = (t >= o) ? sh[t - o] : 0;
      __syncthreads();
      sh[t] += add;
      __syncthreads();
    }
    int incl = sh[t];
    int carry = carry_s;
    if (i < N){ int ex = carry + incl - v; row_ptr[i] = ex; cursor[i] = ex; }
    __syncthreads();
    if (t == 1023) carry_s = carry + incl;
    __syncthreads();
  }
  if (t == 0) row_ptr[N] = carry_s;
}

__global__ void scatter_kernel(const int* __restrict__ dst, int* __restrict__ cursor,
                               int* __restrict__ eids, int E){
  int i = blockIdx.x * 256 + threadIdx.x;
  if (i < E){
    int pos = atomicAdd(&cursor[dst[i]], 1);
    eids[pos] = i;
  }
}

// ---------------- head helper ----------------
__global__ void wlscale_kernel(const float* __restrict__ Wl, const float* __restrict__ bl,
                               const float* __restrict__ scale, float* __restrict__ wlsc){
  int c = threadIdx.x;
  float s = 0.f;
  #pragma unroll
  for (int j = 0; j < 8; j++) s += Wl[c * 8 + j] * scale[j];
  wlsc[c] = s;
  if (c == 0){
    float b = 0.f;
    #pragma unroll
    for (int j = 0; j < 8; j++) b += bl[j] * scale[j];
    wlsc[256] = b;
  }
}

// ---------------- weight pack: Wp[l][ncat][k] = W(l)[k][n] bf16 (transpose) --------
__global__ __launch_bounds__(256) void pack_w_kernel(
    const float* __restrict__ Wq, const float* __restrict__ Wk,
    const float* __restrict__ Wv, const float* __restrict__ Ws,
    unsigned short* __restrict__ Wp)
{
  __shared__ float t[32][33];
  int l   = blockIdx.z;
  int k0  = blockIdx.x * 32;
  int n0g = blockIdx.y * 32;
  int w   = n0g >> 8;
  int n0  = n0g & 255;
  const float* W = ((w == 0) ? Wq : (w == 1) ? Wk : (w == 2) ? Wv : Ws) + (size_t)l * 65536;
  int rr = threadIdx.x >> 3;
  int cc = (threadIdx.x & 7) * 4;
  float4 vv = *(const float4*)&W[(size_t)(k0 + rr) * 256 + n0 + cc];
  t[rr][cc + 0] = vv.x; t[rr][cc + 1] = vv.y; t[rr][cc + 2] = vv.z; t[rr][cc + 3] = vv.w;
  __syncthreads();
  ushort4 o;
  o.x = f2bf(t[cc + 0][rr]);
  o.y = f2bf(t[cc + 1][rr]);
  o.z = f2bf(t[cc + 2][rr]);
  o.w = f2bf(t[cc + 3][rr]);
  *(ushort4*)&Wp[(size_t)l * 262144 + (size_t)(n0g + rr) * 256 + k0 + cc] = o;
}

__global__ void pack_b_kernel(const float* __restrict__ bq, const float* __restrict__ bk,
                              const float* __restrict__ bv, const float* __restrict__ bs,
                              float* __restrict__ bp){
  int i = blockIdx.x * 256 + threadIdx.x;
  if (i < 15 * 256){
    int l = i >> 8, n = i & 255;
    bp[l * 1024 + 0   + n] = bq[i];
    bp[l * 1024 + 256 + n] = bk[i];
    bp[l * 1024 + 512 + n] = bv[i];
    bp[l * 1024 + 768 + n] = bs[i];
  }
}

// ---------------- conv1 GEMMs: [N,16]x[16,256]x4 -> qkvb bf16 [N][768], sl fp32 ----
__global__ __launch_bounds__(256) void gemm1_kernel(
    const float* __restrict__ A,
    const float* __restrict__ W0, const float* __restrict__ W1,
    const float* __restrict__ W2, const float* __restrict__ W3,
    const float* __restrict__ B0, const float* __restrict__ B1,
    const float* __restrict__ B2, const float* __restrict__ B3,
    unsigned short* __restrict__ qkvb, float* __restrict__ sl, int N)
{
  __shared__ float As[64][16];
  int nb = blockIdx.x * 64;
  {
    int row = nb + (threadIdx.x >> 2);
    int qq = (threadIdx.x & 3) * 4;
    float4 a = make_float4(0.f, 0.f, 0.f, 0.f);
    if (row < N) a = *(const float4*)&A[row * 16 + qq];
    *(float4*)&As[threadIdx.x >> 2][qq] = a;
  }
  __syncthreads();
  int col = threadIdx.x;
  #pragma unroll
  for (int w = 0; w < 4; w++){
    const float* W  = (w == 0) ? W0 : (w == 1) ? W1 : (w == 2) ? W2 : W3;
    const float* Bi = (w == 0) ? B0 : (w == 1) ? B1 : (w == 2) ? B2 : B3;
    float wr[16];
    #pragma unroll
    for (int kk = 0; kk < 16; kk++) wr[kk] = W[kk * 256 + col];
    float bias = Bi[col];
    for (int r = 0; r < 64; r++){
      int row = nb + r;
      if (row >= N) break;
      float acc = bias;
      #pragma unroll
      for (int kk = 0; kk < 16; kk++) acc += As[r][kk] * wr[kk];
      if (w < 3) qkvb[(size_t)row * 768 + w * 256 + col] = f2bf(acc);
      else       sl[(size_t)row * 256 + col] = acc;
    }
  }
}

// ---------------- main MFMA GEMM ----------------
// cols 0..767 (q|k|v) -> bf16 qkvb[M][768]; cols 768..1023 (s) -> fp32 sl[M][256]
__global__ __launch_bounds__(256, 2) void gemm_mfma_kernel(
    const unsigned short* __restrict__ A,   // [Mpad][256] bf16
    const unsigned short* __restrict__ Wp,  // [1024][256] bf16 (W^T)
    const float* __restrict__ bp,           // [1024]
    unsigned short* __restrict__ qkvb,      // [M][768] bf16
    float* __restrict__ sl,                 // [M][256]
    int M)
{
  __shared__ unsigned short lds[2 * 128 * 64];
  unsigned short* ldsA = lds;
  unsigned short* ldsB = lds + 128 * 64;
  const int tid  = threadIdx.x;
  const int wave = tid >> 6, lane = tid & 63;
  const int wm = wave >> 1, wn = wave & 1;
  const int m0 = blockIdx.x * 128;
  const int n0 = blockIdx.y * 128;

  f32x4 acc[4][4] = {};

  const int srow  = lane >> 3;
  const int sc16  = lane & 7;
  const int skgrp = sc16 ^ (srow & 7);

  for (int k0 = 0; k0 < 256; k0 += 64){
    #pragma unroll
    for (int it = 0; it < 4; ++it){
      int lrow = wave * 32 + it * 8;
      const unsigned short* gA = A + (size_t)(m0 + lrow + srow) * 256 + k0 + skgrp * 8;
      __builtin_amdgcn_global_load_lds((const __attribute__((address_space(1))) unsigned int*)gA,
          (__attribute__((address_space(3))) unsigned int*)(ldsA + lrow * 64), 16, 0, 0);
      const unsigned short* gB = Wp + (size_t)(n0 + lrow + srow) * 256 + k0 + skgrp * 8;
      __builtin_amdgcn_global_load_lds((const __attribute__((address_space(1))) unsigned int*)gB,
          (__attribute__((address_space(3))) unsigned int*)(ldsB + lrow * 64), 16, 0, 0);
    }
    __syncthreads();

    bf16x8 af[4][2], bfr[4][2];
    #pragma unroll
    for (int mb = 0; mb < 4; ++mb){
      int r = wm * 64 + mb * 16 + (lane & 15);
      #pragma unroll
      for (int ks = 0; ks < 2; ++ks){
        int kg = ks * 4 + (lane >> 4);
        af[mb][ks] = *(const bf16x8*)&ldsA[r * 64 + ((kg ^ (r & 7)) * 8)];
      }
    }
    #pragma unroll
    for (int nb = 0; nb < 4; ++nb){
      int r = wn * 64 + nb * 16 + (lane & 15);
      #pragma unroll
      for (int ks = 0; ks < 2; ++ks){
        int kg = ks * 4 + (lane >> 4);
        bfr[nb][ks] = *(const bf16x8*)&ldsB[r * 64 + ((kg ^ (r & 7)) * 8)];
      }
    }
    #pragma unroll
    for (int mb = 0; mb < 4; ++mb){
      #pragma unroll
      for (int nb = 0; nb < 4; ++nb){
        acc[mb][nb] = __builtin_amdgcn_mfma_f32_16x16x32_bf16(af[mb][0], bfr[nb][0], acc[mb][nb], 0, 0, 0);
        acc[mb][nb] = __builtin_amdgcn_mfma_f32_16x16x32_bf16(af[mb][1], bfr[nb][1], acc[mb][nb], 0, 0, 0);
      }
    }
    __syncthreads();
  }

  // epilogue. D layout: col=lane&15, row=(lane>>4)*4+r4
  #pragma unroll
  for (int nb = 0; nb < 4; ++nb){
    int col = n0 + wn * 64 + nb * 16 + (lane & 15);
    float bias = bp[col];
    #pragma unroll
    for (int mb = 0; mb < 4; ++mb){
      #pragma unroll
      for (int r4 = 0; r4 < 4; ++r4){
        int row = m0 + wm * 64 + mb * 16 + (lane >> 4) * 4 + r4;
        if (row < M){
          float o = acc[mb][nb][r4] + bias;
          if (col < 768) qkvb[(size_t)row * 768 + col] = f2bf(o);
          else           sl[(size_t)row * 256 + (col - 768)] = o;
        }
      }
    }
  }
}

// ---------------- attention aggregation + residual + fused std/relu ----------------
// one wave per dst node; bf16 q/k/v gathers with one-edge software prefetch
__global__ __launch_bounds__(256) void agg_kernel(
    const unsigned short* __restrict__ qkvb,  // [N][768] bf16 q|k|v
    const float* __restrict__ sl,             // [N][256] fp32 skip
    const float* __restrict__ ea, const float* __restrict__ We,
    const int* __restrict__ src, const int* __restrict__ row_ptr,
    const int* __restrict__ eids,
    const float* __restrict__ h_in, float* __restrict__ h_out,
    unsigned short* __restrict__ h2b, int RESID, int N)
{
  __shared__ float We_s[4 * 256];
  for (int i = threadIdx.x; i < 1024; i += 256) We_s[i] = We[i];
  __syncthreads();
  int wid = threadIdx.x >> 6, lane = threadIdx.x & 63;
  int n = blockIdx.x * 4 + wid;
  if (n >= N) return;
  int c0 = lane * 4;
  float w0 = We_s[c0 + 0], w1 = We_s[256 + c0 + 0], w2 = We_s[512 + c0 + 0], w3 = We_s[768 + c0 + 0];
  float u0 = We_s[c0 + 1], u1 = We_s[256 + c0 + 1], u2 = We_s[512 + c0 + 1], u3 = We_s[768 + c0 + 1];
  float p0 = We_s[c0 + 2], p1 = We_s[256 + c0 + 2], p2 = We_s[512 + c0 + 2], p3 = We_s[768 + c0 + 2];
  float r0 = We_s[c0 + 3], r1 = We_s[256 + c0 + 3], r2 = We_s[512 + c0 + 3], r3 = We_s[768 + c0 + 3];

  ushort4 qr = *(const ushort4*)&qkvb[(size_t)n * 768 + c0];
  float qx = b2f(qr.x), qy = b2f(qr.y), qz = b2f(qr.z), qw = b2f(qr.w);

  float m = -INFINITY, ssum = 0.f;
  float a0 = 0.f, a1 = 0.f, a2 = 0.f, a3 = 0.f;
  int e0 = row_ptr[n], e1 = row_ptr[n + 1];

  float4 ea_nxt; ushort4 k_nxt, v_nxt;
  if (e0 < e1){
    int e = eids[e0];
    int s = src[e];
    ea_nxt = *(const float4*)&ea[e * 4];
    k_nxt = *(const ushort4*)&qkvb[(size_t)s * 768 + 256 + c0];
    v_nxt = *(const ushort4*)&qkvb[(size_t)s * 768 + 512 + c0];
  }
  for (int ie = e0; ie < e1; ++ie){
    float4 eav = ea_nxt; ushort4 kr = k_nxt, vr = v_nxt;
    if (ie + 1 < e1){
      int e = eids[ie + 1];
      int s = src[e];
      ea_nxt = *(const float4*)&ea[e * 4];
      k_nxt = *(const ushort4*)&qkvb[(size_t)s * 768 + 256 + c0];
      v_nxt = *(const ushort4*)&qkvb[(size_t)s * 768 + 512 + c0];
    }
    float em0 = eav.x * w0 + eav.y * w1 + eav.z * w2 + eav.w * w3;
    float em1 = eav.x * u0 + eav.y * u1 + eav.z * u2 + eav.w * u3;
    float em2 = eav.x * p0 + eav.y * p1 + eav.z * p2 + eav.w * p3;
    float em3 = eav.x * r0 + eav.y * r1 + eav.z * r2 + eav.w * r3;
    float k0f = b2f(kr.x) + em0, k1f = b2f(kr.y) + em1;
    float k2f = b2f(kr.z) + em2, k3f = b2f(kr.w) + em3;
    float part = qx * k0f + qy * k1f + qz * k2f + qw * k3f;
    part = wred_sum(part);
    float alpha = part * (1.f / 16.f);
    float mn = fmaxf(m, alpha);
    float corr = expf(m - mn);
    float wgt  = expf(alpha - mn);
    ssum = ssum * corr + wgt;
    a0 = a0 * corr + wgt * (b2f(vr.x) + em0);
    a1 = a1 * corr + wgt * (b2f(vr.y) + em1);
    a2 = a2 * corr + wgt * (b2f(vr.z) + em2);
    a3 = a3 * corr + wgt * (b2f(vr.w) + em3);
    m = mn;
  }
  float inv = 1.f / (ssum + 1e-16f);
  float4 slv = *(const float4*)&sl[(size_t)n * 256 + c0];
  float y0 = a0 * inv + slv.x;
  float y1 = a1 * inv + slv.y;
  float y2 = a2 * inv + slv.z;
  float y3 = a3 * inv + slv.w;
  float o0, o1, o2, o3;
  if (RESID){
    float4 hp = *(const float4*)&h_in[(size_t)n * 256 + c0];
    o0 = hp.x + y0; o1 = hp.y + y1; o2 = hp.z + y2; o3 = hp.w + y3;
  } else {
    o0 = y0; o1 = y1; o2 = y2; o3 = y3;
  }
  float4 ho; ho.x = o0; ho.y = o1; ho.z = o2; ho.w = o3;
  *(float4*)&h_out[(size_t)n * 256 + c0] = ho;
  float mean = wred_sum(o0 + o1 + o2 + o3) * (1.f / 256.f);
  float d0 = o0 - mean, d1 = o1 - mean, d2 = o2 - mean, d3 = o3 - mean;
  float var = wred_sum(d0 * d0 + d1 * d1 + d2 * d2 + d3 * d3) * (1.f / 255.f);
  float invstd = 1.f / sqrtf(var);
  ushort4 hb;
  hb.x = f2bf(fmaxf(o0 * invstd, 0.f));
  hb.y = f2bf(fmaxf(o1 * invstd, 0.f));
  hb.z = f2bf(fmaxf(o2 * invstd, 0.f));
  hb.w = f2bf(fmaxf(o3 * invstd, 0.f));
  *(ushort4*)&h2b[(size_t)n * 256 + c0] = hb;
}

// ---------------- output head ----------------
__global__ __launch_bounds__(256) void head_kernel(const float* __restrict__ h,
                                                   const float* __restrict__ wlsc,
                                                   float* __restrict__ out, int N){
  int wid = threadIdx.x >> 6, lane = threadIdx.x & 63;
  int n = blockIdx.x * 4 + wid;
  if (n >= N) return;
  int c0 = lane * 4;
  float4 hv = *(const float4*)&h[(size_t)n * 256 + c0];
  float4 wv = *(const float4*)&wlsc[c0];
  float p = hv.x * wv.x + hv.y * wv.y + hv.z * wv.z + hv.w * wv.w;
  p = wred_sum(p);
  if (lane == 0) out[n] = p * (1.f / sqrtf(15.f)) + wlsc[256];
}

// ---------------- launch ----------------
extern "C" void kernel_launch(void* const* d_in, const int* in_sizes, int n_in,
                              void* d_out, int out_size, void* d_ws, size_t ws_size,
                              hipStream_t stream)
{
  const float* x     = (const float*)d_in[0];
  const int*   eidx  = (const int*)d_in[1];
  const float* Wq1 = (const float*)d_in[3];  const float* bq1 = (const float*)d_in[4];
  const float* Wk1 = (const float*)d_in[5];  const float* bk1 = (const float*)d_in[6];
  const float* Wv1 = (const float*)d_in[7];  const float* bv1 = (const float*)d_in[8];
  const float* We1 = (const float*)d_in[9];
  const float* Ws1 = (const float*)d_in[10]; const float* bs1 = (const float*)d_in[11];
  const float* Wq = (const float*)d_in[12];  const float* bq = (const float*)d_in[13];
  const float* Wk = (const float*)d_in[14];  const float* bk = (const float*)d_in[15];
  const float* Wv = (const float*)d_in[16];  const float* bv = (const float*)d_in[17];
  const float* We = (const float*)d_in[18];
  const float* Ws = (const float*)d_in[19];  const float* bs = (const float*)d_in[20];
  const float* Wl = (const float*)d_in[21];  const float* bl = (const float*)d_in[22];
  const float* scale = (const float*)d_in[23];
  (void)n_in; (void)ws_size;

  int N = in_sizes[0] / 16;
  int E = in_sizes[2] / 4;
  int Mpad = (N + 127) & ~127;
  float* out = (float*)d_out;
  (void)out_size;

  char* p = (char*)d_ws;
  auto alloc = [&](size_t bytes) -> char* {
    char* r = p; p += (bytes + 255) & ~(size_t)255; return r;
  };
  float* hx   = (float*)alloc((size_t)N * 16 * 4);
  float* ea   = (float*)alloc((size_t)E * 4 * 4);
  float* h    = (float*)alloc((size_t)N * 256 * 4);
  unsigned short* h2b = (unsigned short*)alloc((size_t)Mpad * 256 * 2);
  unsigned short* qkvb = (unsigned short*)alloc((size_t)N * 768 * 2);
  float* sl   = (float*)alloc((size_t)N * 256 * 4);
  unsigned short* Wp  = (unsigned short*)alloc((size_t)15 * 1024 * 256 * 2);
  float* bp   = (float*)alloc((size_t)15 * 1024 * 4);
  float* wlsc = (float*)alloc(257 * 4);
  int* counts  = (int*)alloc((size_t)N * 4);
  int* cursor  = (int*)alloc((size_t)N * 4);
  int* row_ptr = (int*)alloc(((size_t)N + 1) * 4);
  int* eids    = (int*)alloc((size_t)E * 4);

  const int* srcp = eidx;
  const int* dstp = eidx + E;

  int nx = N * 16, ne = E * 4;
  int big = nx > ne ? nx : ne;

  zero_kernel<<<(N + 255) / 256, 256, 0, stream>>>(counts, N);
  prep_kernel<<<(big + 255) / 256, 256, 0, stream>>>(x, (const float*)d_in[2], hx, ea, nx, ne);
  hist_kernel<<<(E + 255) / 256, 256, 0, stream>>>(dstp, counts, E);
  scan_kernel<<<1, 1024, 0, stream>>>(counts, row_ptr, cursor, N);
  scatter_kernel<<<(E + 255) / 256, 256, 0, stream>>>(dstp, cursor, eids, E);
  wlscale_kernel<<<1, 256, 0, stream>>>(Wl, bl, scale, wlsc);
  pack_w_kernel<<<dim3(8, 32, 15), 256, 0, stream>>>(Wq, Wk, Wv, Ws, Wp);
  pack_b_kernel<<<15, 256, 0, stream>>>(bq, bk, bv, bs, bp);

  // conv1
  gemm1_kernel<<<(N + 63) / 64, 256, 0, stream>>>(hx, Wq1, Wk1, Wv1, Ws1,
                                                  bq1, bk1, bv1, bs1, qkvb, sl, N);
  agg_kernel<<<(N + 3) / 4, 256, 0, stream>>>(qkvb, sl, ea, We1, srcp, row_ptr, eids,
                                              h, h, h2b, 0, N);

  // 15 residual blocks
  for (int l = 0; l < 15; l++){
    gemm_mfma_kernel<<<dim3(Mpad / 128, 8), 256, 0, stream>>>(
        h2b, Wp + (size_t)l * 262144, bp + (size_t)l * 1024, qkvb, sl, N);
    agg_kernel<<<(N + 3) / 4, 256, 0, stream>>>(qkvb, sl, ea, We + (size_t)l * 1024,
                                                srcp, row_ptr, eids, h, h, h2b, 1, N);
  }

  head_kernel<<<(N + 3) / 4, 256, 0, stream>>>(h, wlsc, out, N);
}